// Round 1
// baseline (2085.887 us; speedup 1.0000x reference)
//
#include <hip/hip_runtime.h>
#include <hip/hip_bf16.h>

typedef __bf16 bf16x8 __attribute__((ext_vector_type(8)));
typedef float f32x4 __attribute__((ext_vector_type(4)));

// d_out layout (f32): hs[128][64][1024] | h_n[64][1024] | c_n[64][1024]
#define HN_OFF 8388608u
#define CN_OFF 8454144u

__device__ __forceinline__ float bf2f(ushort u) {
  union { unsigned int i; float f; } x; x.i = ((unsigned int)u) << 16; return x.f;
}
__device__ __forceinline__ ushort f2bf(float f) {
  union { float f; unsigned int i; } x; x.f = f;
  unsigned int r = x.i + 0x7FFFu + ((x.i >> 16) & 1u);
  return (ushort)(r >> 16);
}

// ---------------- f32 -> bf16 converters ----------------
__global__ __launch_bounds__(256) void conv_copy(const float* __restrict__ s,
                                                 ushort* __restrict__ d, int n4) {
  int i = blockIdx.x * 256 + threadIdx.x;
  if (i < n4) {
    float4 v = reinterpret_cast<const float4*>(s)[i];
    ushort4 o; o.x = f2bf(v.x); o.y = f2bf(v.y); o.z = f2bf(v.z); o.w = f2bf(v.w);
    reinterpret_cast<ushort4*>(d)[i] = o;
  }
}

// Extract W_a = W_ih[:, 512:1024] -> bf16 [4096][512]
__global__ __launch_bounds__(256) void conv_wa(const float* __restrict__ Wih,
                                               ushort* __restrict__ Wa) {
  int t = blockIdx.x * 256 + threadIdx.x;  // 4096*128 threads
  int g = t >> 7, c = t & 127;
  float4 v = *reinterpret_cast<const float4*>(Wih + (size_t)g * 1024 + 512 + c * 4);
  ushort4 o; o.x = f2bf(v.x); o.y = f2bf(v.y); o.z = f2bf(v.z); o.w = f2bf(v.w);
  *reinterpret_cast<ushort4*>(Wa + (size_t)g * 512 + c * 4) = o;
}

// ---------------- base[g][b] = input[b]·W_x[g] + b_ih[g] + b_hh[g] ----------------
__global__ __launch_bounds__(256) void base_kernel(const float* __restrict__ x,
    const float* __restrict__ Wih, const float* __restrict__ bih,
    const float* __restrict__ bhh, float* __restrict__ baseT) {
  int t = blockIdx.x * 256 + threadIdx.x;  // 4096*64 threads
  int g = t >> 6, b = t & 63;
  const float4* xv = reinterpret_cast<const float4*>(x + (size_t)b * 512);
  const float4* wv = reinterpret_cast<const float4*>(Wih + (size_t)g * 1024);
  float s = 0.f;
  #pragma unroll 4
  for (int a = 0; a < 128; ++a) {
    float4 xa = xv[a], wa = wv[a];
    s += xa.x * wa.x + xa.y * wa.y + xa.z * wa.z + xa.w * wa.w;
  }
  baseT[t] = s + bih[g] + bhh[g];
}

// ---------------- pre[g][lb] = sum_a Wa[g][a]*acts[lb][a] + base[g][lb%64] ----------------
// M=4096 (g), N=8192 (lb), K=512. 128x128 tile, BK=64, 4 waves 2x2.
__global__ __launch_bounds__(256, 1) void gemm_pre(
    const ushort* __restrict__ A,    // Wa bf16 [4096][512]
    const ushort* __restrict__ B,    // acts bf16 [8192][512]
    const float* __restrict__ baseT, // [4096][64]
    ushort* __restrict__ C) {        // pre bf16 [4096][8192]
  __shared__ ushort At[128 * 64];
  __shared__ ushort Bt[128 * 64];
  const int tid = threadIdx.x;
  const int m0 = blockIdx.x * 128;
  const int n0 = blockIdx.y * 128;
  const int wave = tid >> 6, lane = tid & 63;
  const int wm = wave >> 1, wn = wave & 1;
  const int q = lane >> 4, lc = lane & 15;

  f32x4 acc[4][4];
  #pragma unroll
  for (int mt = 0; mt < 4; ++mt)
    #pragma unroll
    for (int nt = 0; nt < 4; ++nt)
      acc[mt][nt] = (f32x4){0.f, 0.f, 0.f, 0.f};

  for (int k0 = 0; k0 < 512; k0 += 64) {
    __syncthreads();
    for (int idx = tid; idx < 1024; idx += 256) {
      int r = idx >> 3, ch = idx & 7;
      *reinterpret_cast<uint4*>(&At[r * 64 + (ch ^ (r & 7)) * 8]) =
          *reinterpret_cast<const uint4*>(A + (size_t)(m0 + r) * 512 + k0 + ch * 8);
      *reinterpret_cast<uint4*>(&Bt[r * 64 + (ch ^ (r & 7)) * 8]) =
          *reinterpret_cast<const uint4*>(B + (size_t)(n0 + r) * 512 + k0 + ch * 8);
    }
    __syncthreads();
    #pragma unroll
    for (int kk = 0; kk < 2; ++kk) {
      bf16x8 af[4], bfr[4];
      #pragma unroll
      for (int mt = 0; mt < 4; ++mt) {
        int r = wm * 64 + mt * 16 + lc;
        af[mt] = *reinterpret_cast<const bf16x8*>(&At[r * 64 + ((kk * 4 + q) ^ (r & 7)) * 8]);
      }
      #pragma unroll
      for (int nt = 0; nt < 4; ++nt) {
        int r = wn * 64 + nt * 16 + lc;
        bfr[nt] = *reinterpret_cast<const bf16x8*>(&Bt[r * 64 + ((kk * 4 + q) ^ (r & 7)) * 8]);
      }
      #pragma unroll
      for (int mt = 0; mt < 4; ++mt)
        #pragma unroll
        for (int nt = 0; nt < 4; ++nt)
          acc[mt][nt] = __builtin_amdgcn_mfma_f32_16x16x32_bf16(af[mt], bfr[nt], acc[mt][nt], 0, 0, 0);
    }
  }
  #pragma unroll
  for (int mt = 0; mt < 4; ++mt) {
    #pragma unroll
    for (int nt = 0; nt < 4; ++nt) {
      int g = m0 + wm * 64 + mt * 16 + q * 4;
      int lb = n0 + wn * 64 + nt * 16 + lc;
      int b = lb & 63;
      #pragma unroll
      for (int i = 0; i < 4; ++i) {
        float v = acc[mt][nt][i] + baseT[(size_t)(g + i) * 64 + b];
        C[(size_t)(g + i) * 8192 + lb] = f2bf(v);
      }
    }
  }
}

// ---------------- persistent LSTM recurrence ----------------
// 128 blocks x 256 threads. Block owns 8 hidden units (32 W_hh rows in LDS).
// Grid barrier: monotonic device-scope atomic counter.
__global__ __launch_bounds__(256, 1) void lstm_rec(
    const ushort* __restrict__ Whh,  // bf16 [4096][1024]
    const ushort* __restrict__ pre,  // bf16 [4096][8192]
    const float* __restrict__ c0,    // f32 [64][1024]
    ushort* __restrict__ hbuf,       // bf16 [2][64][1024]
    float* __restrict__ out,
    int* __restrict__ bar) {
  __shared__ ushort wl[32 * 1024];  // 64 KB, XOR-swizzled
  const int tid = threadIdx.x;
  const int bid = blockIdx.x;
  const int j0 = bid * 8;

  // Stage 32 W_hh rows: local row c -> global row j0 + (c&7) + (c>>3)*1024
  for (int idx = tid; idx < 4096; idx += 256) {
    int c = idx >> 7;
    int ch = idx & 127;  // 16B chunk within row
    int g = j0 + (c & 7) + ((c >> 3) << 10);
    uint4 v = *reinterpret_cast<const uint4*>(Whh + (size_t)g * 1024 + ch * 8);
    *reinterpret_cast<uint4*>(&wl[c * 1024 + (ch ^ (c & 7)) * 8]) = v;
  }

  const int wave = tid >> 6;
  const int lane = tid & 63;
  const int q = lane >> 4;
  const int lc = lane & 15;
  const int bbase = wave * 16 + q * 4;  // acc row base (batch)
  const bool low = (lc < 8);
  const int j = j0 + (lc & 7);
  const int ga = j0 + (lc & 7) + ((lc >> 3) << 10);  // gate row for acc0 col
  const int gb = ga + 2048;                          // for acc1 col

  float cst[4];
  #pragma unroll
  for (int i = 0; i < 4; ++i)
    cst[i] = low ? c0[(size_t)(bbase + i) * 1024 + j] : 0.f;

  __syncthreads();

  for (int t = 0; t < 128; ++t) {
    const ushort* hp = hbuf + (size_t)(t & 1) * 65536;
    ushort* hnx = hbuf + (size_t)((t + 1) & 1) * 65536;

    // acc init = pre (bf16) for this step
    f32x4 acc0, acc1;
    {
      ushort4 pa = *reinterpret_cast<const ushort4*>(pre + (size_t)ga * 8192 + t * 64 + bbase);
      ushort4 pb = *reinterpret_cast<const ushort4*>(pre + (size_t)gb * 8192 + t * 64 + bbase);
      acc0[0] = bf2f(pa.x); acc0[1] = bf2f(pa.y); acc0[2] = bf2f(pa.z); acc0[3] = bf2f(pa.w);
      acc1[0] = bf2f(pb.x); acc1[1] = bf2f(pb.y); acc1[2] = bf2f(pb.z); acc1[3] = bf2f(pb.w);
    }

    // gates[64 x 32] += h[64 x 1024] @ Whh_slice^T
    const ushort* hrow = hp + (size_t)(wave * 16 + lc) * 1024;
    #pragma unroll
    for (int kk = 0; kk < 32; ++kk) {
      bf16x8 af = *reinterpret_cast<const bf16x8*>(hrow + kk * 32 + q * 8);
      bf16x8 b0 = *reinterpret_cast<const bf16x8*>(&wl[lc * 1024 + ((kk * 4 + q) ^ (lc & 7)) * 8]);
      bf16x8 b1 = *reinterpret_cast<const bf16x8*>(&wl[(16 + lc) * 1024 + ((kk * 4 + q) ^ (lc & 7)) * 8]);
      acc0 = __builtin_amdgcn_mfma_f32_16x16x32_bf16(af, b0, acc0, 0, 0, 0);
      acc1 = __builtin_amdgcn_mfma_f32_16x16x32_bf16(af, b1, acc1, 0, 0, 0);
    }

    // join i/f and g/o across lane pairs (l <-> l^8), then LSTM cell
    float fv[4], ov[4];
    #pragma unroll
    for (int i = 0; i < 4; ++i) {
      fv[i] = __shfl_xor(acc0[i], 8, 64);
      ov[i] = __shfl_xor(acc1[i], 8, 64);
    }
    if (low) {
      #pragma unroll
      for (int i = 0; i < 4; ++i) {
        float ig = 1.f / (1.f + __expf(-acc0[i]));
        float fg = 1.f / (1.f + __expf(-fv[i]));
        float gg = tanhf(acc1[i]);
        float og = 1.f / (1.f + __expf(-ov[i]));
        float cn = fg * cst[i] + ig * gg;
        float hv = og * tanhf(cn);
        cst[i] = cn;
        int b = bbase + i;
        hnx[(size_t)b * 1024 + j] = f2bf(hv);
        out[((size_t)t * 64 + b) * 1024 + j] = hv;
        if (t == 127) {
          out[HN_OFF + (size_t)b * 1024 + j] = hv;
          out[CN_OFF + (size_t)b * 1024 + j] = cn;
        }
      }
    }

    // grid-wide barrier (monotonic counter, device scope)
    __syncthreads();
    if (tid == 0) {
      __threadfence();
      __hip_atomic_fetch_add(bar, 1, __ATOMIC_RELEASE, __HIP_MEMORY_SCOPE_AGENT);
      const int target = 128 * (t + 1);
      while (__hip_atomic_load(bar, __ATOMIC_ACQUIRE, __HIP_MEMORY_SCOPE_AGENT) < target) {
        __builtin_amdgcn_s_sleep(8);
      }
      __threadfence();
    }
    __syncthreads();
  }
}

extern "C" void kernel_launch(void* const* d_in, const int* in_sizes, int n_in,
                              void* d_out, int out_size, void* d_ws, size_t ws_size,
                              hipStream_t stream) {
  const float* input = (const float*)d_in[0];  // (64,512)
  const float* acts  = (const float*)d_in[1];  // (128,64,512)
  const float* h0    = (const float*)d_in[2];  // (64,1024)
  const float* c0    = (const float*)d_in[3];  // (64,1024)
  const float* Wih   = (const float*)d_in[4];  // (4096,1024)
  const float* Whh   = (const float*)d_in[5];  // (4096,1024)
  const float* bih   = (const float*)d_in[6];  // (4096)
  const float* bhh   = (const float*)d_in[7];  // (4096)
  float* out = (float*)d_out;

  char* ws = (char*)d_ws;
  ushort* pre   = (ushort*)(ws);                 // 67,108,864 B
  ushort* actsb = (ushort*)(ws + 67108864);      //  8,388,608 B
  ushort* Wab   = (ushort*)(ws + 75497472);      //  4,194,304 B
  ushort* Whhb  = (ushort*)(ws + 79691776);      //  8,388,608 B
  float*  baseT = (float*) (ws + 88080384);      //  1,048,576 B
  ushort* hbuf  = (ushort*)(ws + 89128960);      //    262,144 B
  int*    bar   = (int*)   (ws + 89391104);      //        256 B

  hipMemsetAsync(bar, 0, 256, stream);
  conv_copy<<<4096, 256, 0, stream>>>(acts, actsb, 1048576);
  conv_copy<<<4096, 256, 0, stream>>>(Whh, Whhb, 1048576);
  conv_copy<<<64, 256, 0, stream>>>(h0, hbuf, 16384);
  conv_wa<<<2048, 256, 0, stream>>>(Wih, Wab);
  base_kernel<<<1024, 256, 0, stream>>>(input, Wih, bih, bhh, baseT);
  gemm_pre<<<dim3(32, 64), 256, 0, stream>>>(Wab, actsb, baseT, pre);
  lstm_rec<<<128, 256, 0, stream>>>(Whhb, pre, c0, hbuf, out, bar);
}

// Round 2
// 1282.393 us; speedup vs baseline: 1.6266x; 1.6266x over previous
//
#include <hip/hip_runtime.h>
#include <hip/hip_bf16.h>

typedef __bf16 bf16x8 __attribute__((ext_vector_type(8)));
typedef float f32x4 __attribute__((ext_vector_type(4)));

// d_out layout (f32): hs[128][64][1024] | h_n[64][1024] | c_n[64][1024]
#define HN_OFF 8388608u
#define CN_OFF 8454144u

__device__ __forceinline__ float bf2f(ushort u) {
  union { unsigned int i; float f; } x; x.i = ((unsigned int)u) << 16; return x.f;
}
__device__ __forceinline__ ushort f2bf(float f) {
  union { float f; unsigned int i; } x; x.f = f;
  unsigned int r = x.i + 0x7FFFu + ((x.i >> 16) & 1u);
  return (ushort)(r >> 16);
}

// ---------------- f32 -> bf16 converters ----------------
__global__ __launch_bounds__(256) void conv_copy(const float* __restrict__ s,
                                                 ushort* __restrict__ d, int n4) {
  int i = blockIdx.x * 256 + threadIdx.x;
  if (i < n4) {
    float4 v = reinterpret_cast<const float4*>(s)[i];
    ushort4 o; o.x = f2bf(v.x); o.y = f2bf(v.y); o.z = f2bf(v.z); o.w = f2bf(v.w);
    reinterpret_cast<ushort4*>(d)[i] = o;
  }
}

// Extract W_a = W_ih[:, 512:1024] -> bf16 [4096][512]
__global__ __launch_bounds__(256) void conv_wa(const float* __restrict__ Wih,
                                               ushort* __restrict__ Wa) {
  int t = blockIdx.x * 256 + threadIdx.x;  // 4096*128 threads
  int g = t >> 7, c = t & 127;
  float4 v = *reinterpret_cast<const float4*>(Wih + (size_t)g * 1024 + 512 + c * 4);
  ushort4 o; o.x = f2bf(v.x); o.y = f2bf(v.y); o.z = f2bf(v.z); o.w = f2bf(v.w);
  *reinterpret_cast<ushort4*>(Wa + (size_t)g * 512 + c * 4) = o;
}

// ---------------- base[g][b] = input[b]·W_x[g] + b_ih[g] + b_hh[g] ----------------
__global__ __launch_bounds__(256) void base_kernel(const float* __restrict__ x,
    const float* __restrict__ Wih, const float* __restrict__ bih,
    const float* __restrict__ bhh, float* __restrict__ baseT) {
  int t = blockIdx.x * 256 + threadIdx.x;  // 4096*64 threads
  int g = t >> 6, b = t & 63;
  const float4* xv = reinterpret_cast<const float4*>(x + (size_t)b * 512);
  const float4* wv = reinterpret_cast<const float4*>(Wih + (size_t)g * 1024);
  float s = 0.f;
  #pragma unroll 4
  for (int a = 0; a < 128; ++a) {
    float4 xa = xv[a], wa = wv[a];
    s += xa.x * wa.x + xa.y * wa.y + xa.z * wa.z + xa.w * wa.w;
  }
  baseT[t] = s + bih[g] + bhh[g];
}

// ---------------- pre[g][lb] = sum_a Wa[g][a]*acts[lb][a] + base[g][lb%64] ----------------
// M=4096 (g), N=8192 (lb), K=512. 128x128 tile, BK=64, 4 waves 2x2.
__global__ __launch_bounds__(256, 1) void gemm_pre(
    const ushort* __restrict__ A,    // Wa bf16 [4096][512]
    const ushort* __restrict__ B,    // acts bf16 [8192][512]
    const float* __restrict__ baseT, // [4096][64]
    ushort* __restrict__ C) {        // pre bf16 [4096][8192]
  __shared__ ushort At[128 * 64];
  __shared__ ushort Bt[128 * 64];
  const int tid = threadIdx.x;
  const int m0 = blockIdx.x * 128;
  const int n0 = blockIdx.y * 128;
  const int wave = tid >> 6, lane = tid & 63;
  const int wm = wave >> 1, wn = wave & 1;
  const int q = lane >> 4, lc = lane & 15;

  f32x4 acc[4][4];
  #pragma unroll
  for (int mt = 0; mt < 4; ++mt)
    #pragma unroll
    for (int nt = 0; nt < 4; ++nt)
      acc[mt][nt] = (f32x4){0.f, 0.f, 0.f, 0.f};

  for (int k0 = 0; k0 < 512; k0 += 64) {
    __syncthreads();
    for (int idx = tid; idx < 1024; idx += 256) {
      int r = idx >> 3, ch = idx & 7;
      *reinterpret_cast<uint4*>(&At[r * 64 + (ch ^ (r & 7)) * 8]) =
          *reinterpret_cast<const uint4*>(A + (size_t)(m0 + r) * 512 + k0 + ch * 8);
      *reinterpret_cast<uint4*>(&Bt[r * 64 + (ch ^ (r & 7)) * 8]) =
          *reinterpret_cast<const uint4*>(B + (size_t)(n0 + r) * 512 + k0 + ch * 8);
    }
    __syncthreads();
    #pragma unroll
    for (int kk = 0; kk < 2; ++kk) {
      bf16x8 af[4], bfr[4];
      #pragma unroll
      for (int mt = 0; mt < 4; ++mt) {
        int r = wm * 64 + mt * 16 + lc;
        af[mt] = *reinterpret_cast<const bf16x8*>(&At[r * 64 + ((kk * 4 + q) ^ (r & 7)) * 8]);
      }
      #pragma unroll
      for (int nt = 0; nt < 4; ++nt) {
        int r = wn * 64 + nt * 16 + lc;
        bfr[nt] = *reinterpret_cast<const bf16x8*>(&Bt[r * 64 + ((kk * 4 + q) ^ (r & 7)) * 8]);
      }
      #pragma unroll
      for (int mt = 0; mt < 4; ++mt)
        #pragma unroll
        for (int nt = 0; nt < 4; ++nt)
          acc[mt][nt] = __builtin_amdgcn_mfma_f32_16x16x32_bf16(af[mt], bfr[nt], acc[mt][nt], 0, 0, 0);
    }
  }
  #pragma unroll
  for (int mt = 0; mt < 4; ++mt) {
    #pragma unroll
    for (int nt = 0; nt < 4; ++nt) {
      int g = m0 + wm * 64 + mt * 16 + q * 4;
      int lb = n0 + wn * 64 + nt * 16 + lc;
      int b = lb & 63;
      #pragma unroll
      for (int i = 0; i < 4; ++i) {
        float v = acc[mt][nt][i] + baseT[(size_t)(g + i) * 64 + b];
        C[(size_t)(g + i) * 8192 + lb] = f2bf(v);
      }
    }
  }
}

// ---------------- persistent LSTM recurrence ----------------
// 128 blocks x 256 threads. Block owns 8 hidden units (32 W_hh rows in LDS).
// Grid barrier: per-block padded flag array (parallel publish), wave-0 poll.
// h exported via agent-scope L2-bypassing 8B atomic stores (no wbl2 fences);
// read side re-coherenced with one acquire fence (buffer_inv) per step.
__global__ __launch_bounds__(256, 1) void lstm_rec(
    const ushort* __restrict__ Whh,  // bf16 [4096][1024]
    const ushort* __restrict__ pre,  // bf16 [4096][8192]
    const float* __restrict__ c0,    // f32 [64][1024]
    ushort* __restrict__ hbuf,       // bf16 [2][64][1024]
    float* __restrict__ out,
    int* __restrict__ flags) {       // [128][32] ints, 128B-padded
  __shared__ ushort wl[32 * 1024];   // 64 KB, XOR-swizzled W_hh slice
  __shared__ ushort hstage[64 * 8];  // h(t+1) staging: [batch][8 units]
  const int tid = threadIdx.x;
  const int bid = blockIdx.x;
  const int j0 = bid * 8;

  // Stage 32 W_hh rows: local row c -> global row j0 + (c&7) + (c>>3)*1024
  for (int idx = tid; idx < 4096; idx += 256) {
    int c = idx >> 7;
    int ch = idx & 127;  // 16B chunk within row
    int g = j0 + (c & 7) + ((c >> 3) << 10);
    uint4 v = *reinterpret_cast<const uint4*>(Whh + (size_t)g * 1024 + ch * 8);
    *reinterpret_cast<uint4*>(&wl[c * 1024 + (ch ^ (c & 7)) * 8]) = v;
  }

  const int wave = tid >> 6;
  const int lane = tid & 63;
  const int q = lane >> 4;
  const int lc = lane & 15;
  const int bbase = wave * 16 + q * 4;  // acc row base (batch)
  const bool low = (lc < 8);
  const int j = j0 + (lc & 7);
  const int ga = j0 + (lc & 7) + ((lc >> 3) << 10);  // gate row for acc0 col
  const int gb = ga + 2048;                          // for acc1 col

  float cst[4];
  #pragma unroll
  for (int i = 0; i < 4; ++i)
    cst[i] = low ? c0[(size_t)(bbase + i) * 1024 + j] : 0.f;

  __syncthreads();

  // prefetch pre slice for t=0
  ushort4 pa = *reinterpret_cast<const ushort4*>(pre + (size_t)ga * 8192 + bbase);
  ushort4 pb = *reinterpret_cast<const ushort4*>(pre + (size_t)gb * 8192 + bbase);

  for (int t = 0; t < 128; ++t) {
    const ushort* hp = hbuf + (size_t)(t & 1) * 65536;

    // acc init = prefetched pre (bf16) for this step
    f32x4 acc0, acc1;
    acc0[0] = bf2f(pa.x); acc0[1] = bf2f(pa.y); acc0[2] = bf2f(pa.z); acc0[3] = bf2f(pa.w);
    acc1[0] = bf2f(pb.x); acc1[1] = bf2f(pb.y); acc1[2] = bf2f(pb.z); acc1[3] = bf2f(pb.w);

    // issue prefetch of pre for step t+1 (overlaps MFMA + barrier)
    const int tn = (t < 127) ? t + 1 : t;
    pa = *reinterpret_cast<const ushort4*>(pre + (size_t)ga * 8192 + tn * 64 + bbase);
    pb = *reinterpret_cast<const ushort4*>(pre + (size_t)gb * 8192 + tn * 64 + bbase);

    // gates[64 x 32] += h[64 x 1024] @ Whh_slice^T
    const ushort* hrow = hp + (size_t)(wave * 16 + lc) * 1024;
    #pragma unroll
    for (int kk = 0; kk < 32; ++kk) {
      bf16x8 af = *reinterpret_cast<const bf16x8*>(hrow + kk * 32 + q * 8);
      bf16x8 b0 = *reinterpret_cast<const bf16x8*>(&wl[lc * 1024 + ((kk * 4 + q) ^ (lc & 7)) * 8]);
      bf16x8 b1 = *reinterpret_cast<const bf16x8*>(&wl[(16 + lc) * 1024 + ((kk * 4 + q) ^ (lc & 7)) * 8]);
      acc0 = __builtin_amdgcn_mfma_f32_16x16x32_bf16(af, b0, acc0, 0, 0, 0);
      acc1 = __builtin_amdgcn_mfma_f32_16x16x32_bf16(af, b1, acc1, 0, 0, 0);
    }

    // join i/f and g/o across lane pairs (l <-> l^8), then LSTM cell
    float fv[4], ov[4];
    #pragma unroll
    for (int i = 0; i < 4; ++i) {
      fv[i] = __shfl_xor(acc0[i], 8, 64);
      ov[i] = __shfl_xor(acc1[i], 8, 64);
    }
    if (low) {
      #pragma unroll
      for (int i = 0; i < 4; ++i) {
        float ig = 1.f / (1.f + __expf(-acc0[i]));
        float fg = 1.f / (1.f + __expf(-fv[i]));
        float gg = tanhf(acc1[i]);
        float og = 1.f / (1.f + __expf(-ov[i]));
        float cn = fg * cst[i] + ig * gg;
        float hv = og * tanhf(cn);
        cst[i] = cn;
        int b = bbase + i;
        hstage[(size_t)b * 8 + (lc & 7)] = f2bf(hv);
        out[((size_t)t * 64 + b) * 1024 + j] = hv;
        if (t == 127) {
          out[HN_OFF + (size_t)b * 1024 + j] = hv;
          out[CN_OFF + (size_t)b * 1024 + j] = cn;
        }
      }
    }

    if (t == 127) break;  // nobody consumes h(128)

    __syncthreads();  // hstage ready

    // export h(t+1) slice: 128 x 8B agent-scope stores (bypass L2 -> no wbl2)
    if (tid < 128) {
      int b = tid >> 1, half = tid & 1;
      unsigned long long v =
          *reinterpret_cast<const unsigned long long*>(&hstage[b * 8 + half * 4]);
      __hip_atomic_store(
          reinterpret_cast<unsigned long long*>(
              hbuf + (size_t)((t + 1) & 1) * 65536 + (size_t)b * 1024 + j0 + half * 4),
          v, __ATOMIC_RELAXED, __HIP_MEMORY_SCOPE_AGENT);
    }
    // drain own stores to the coherence point before publishing
    asm volatile("s_waitcnt vmcnt(0)" ::: "memory");
    __syncthreads();

    // publish + poll (wave 0 only; 128 padded flags, monotonic)
    if (wave == 0) {
      if (lane == 0)
        __hip_atomic_store(&flags[bid * 32], t + 1, __ATOMIC_RELAXED,
                           __HIP_MEMORY_SCOPE_AGENT);
      const int target = t + 1;
      for (;;) {
        int a = __hip_atomic_load(&flags[lane * 32], __ATOMIC_RELAXED,
                                  __HIP_MEMORY_SCOPE_AGENT);
        int b2 = __hip_atomic_load(&flags[(64 + lane) * 32], __ATOMIC_RELAXED,
                                   __HIP_MEMORY_SCOPE_AGENT);
        if (__all(a >= target && b2 >= target)) break;
        __builtin_amdgcn_s_sleep(1);
      }
      // acquire: invalidate L1/L2 so regular h loads see fresh data
      __builtin_amdgcn_fence(__ATOMIC_ACQUIRE, "agent");
    }
    __syncthreads();
  }
}

extern "C" void kernel_launch(void* const* d_in, const int* in_sizes, int n_in,
                              void* d_out, int out_size, void* d_ws, size_t ws_size,
                              hipStream_t stream) {
  const float* input = (const float*)d_in[0];  // (64,512)
  const float* acts  = (const float*)d_in[1];  // (128,64,512)
  const float* h0    = (const float*)d_in[2];  // (64,1024)
  const float* c0    = (const float*)d_in[3];  // (64,1024)
  const float* Wih   = (const float*)d_in[4];  // (4096,1024)
  const float* Whh   = (const float*)d_in[5];  // (4096,1024)
  const float* bih   = (const float*)d_in[6];  // (4096)
  const float* bhh   = (const float*)d_in[7];  // (4096)
  float* out = (float*)d_out;

  char* ws = (char*)d_ws;
  ushort* pre   = (ushort*)(ws);                 // 67,108,864 B
  ushort* actsb = (ushort*)(ws + 67108864);      //  8,388,608 B
  ushort* Wab   = (ushort*)(ws + 75497472);      //  4,194,304 B
  ushort* Whhb  = (ushort*)(ws + 79691776);      //  8,388,608 B
  float*  baseT = (float*) (ws + 88080384);      //  1,048,576 B
  ushort* hbuf  = (ushort*)(ws + 89128960);      //    262,144 B
  int*    flags = (int*)   (ws + 89391104);      //     16,384 B

  hipMemsetAsync(flags, 0, 16384, stream);
  conv_copy<<<4096, 256, 0, stream>>>(acts, actsb, 1048576);
  conv_copy<<<4096, 256, 0, stream>>>(Whh, Whhb, 1048576);
  conv_copy<<<64, 256, 0, stream>>>(h0, hbuf, 16384);
  conv_wa<<<2048, 256, 0, stream>>>(Wih, Wab);
  base_kernel<<<1024, 256, 0, stream>>>(input, Wih, bih, bhh, baseT);
  gemm_pre<<<dim3(32, 64), 256, 0, stream>>>(Wab, actsb, baseT, pre);
  lstm_rec<<<128, 256, 0, stream>>>(Whhb, pre, c0, hbuf, out, flags);
}

// Round 3
// 1103.773 us; speedup vs baseline: 1.8898x; 1.1618x over previous
//
#include <hip/hip_runtime.h>
#include <hip/hip_bf16.h>

typedef __bf16 bf16x8 __attribute__((ext_vector_type(8)));
typedef float f32x4 __attribute__((ext_vector_type(4)));
typedef unsigned long long ull;

// d_out layout (f32): hs[128][64][1024] | h_n[64][1024] | c_n[64][1024]
#define HN_OFF 8388608u
#define CN_OFF 8454144u

__device__ __forceinline__ float bf2f(ushort u) {
  union { unsigned int i; float f; } x; x.i = ((unsigned int)u) << 16; return x.f;
}
__device__ __forceinline__ ushort f2bf(float f) {
  union { float f; unsigned int i; } x; x.f = f;
  unsigned int r = x.i + 0x7FFFu + ((x.i >> 16) & 1u);
  return (ushort)(r >> 16);
}

// ---------------- f32 -> bf16 converters ----------------
__global__ __launch_bounds__(256) void conv_copy(const float* __restrict__ s,
                                                 ushort* __restrict__ d, int n4) {
  int i = blockIdx.x * 256 + threadIdx.x;
  if (i < n4) {
    float4 v = reinterpret_cast<const float4*>(s)[i];
    ushort4 o; o.x = f2bf(v.x); o.y = f2bf(v.y); o.z = f2bf(v.z); o.w = f2bf(v.w);
    reinterpret_cast<ushort4*>(d)[i] = o;
  }
}

// h0 (64x1024 f32) -> blocked bf16 layout [bg(4)][kk(32)][lane(64)][8]
// element (b, j) -> ((b>>4)*32 + (j>>5))*512 + ((j>>3)&3)*128 + (b&15)*8 + (j&7)
__global__ __launch_bounds__(256) void conv_h0(const float* __restrict__ h0,
                                               ushort* __restrict__ hb) {
  int t = blockIdx.x * 256 + threadIdx.x;  // 8192 threads: b = t>>7, chunk c = t&127
  int b = t >> 7, c = t & 127;             // j = c*8
  float4 v0 = *reinterpret_cast<const float4*>(h0 + (size_t)b * 1024 + c * 8);
  float4 v1 = *reinterpret_cast<const float4*>(h0 + (size_t)b * 1024 + c * 8 + 4);
  size_t de = ((size_t)(b >> 4) * 32 + (c >> 2)) * 512 + (size_t)(c & 3) * 128 + (b & 15) * 8;
  ushort* d = hb + de;
  d[0] = f2bf(v0.x); d[1] = f2bf(v0.y); d[2] = f2bf(v0.z); d[3] = f2bf(v0.w);
  d[4] = f2bf(v1.x); d[5] = f2bf(v1.y); d[6] = f2bf(v1.z); d[7] = f2bf(v1.w);
}

// Extract W_a = W_ih[:, 512:1024] -> bf16 [4096][512]
__global__ __launch_bounds__(256) void conv_wa(const float* __restrict__ Wih,
                                               ushort* __restrict__ Wa) {
  int t = blockIdx.x * 256 + threadIdx.x;  // 4096*128 threads
  int g = t >> 7, c = t & 127;
  float4 v = *reinterpret_cast<const float4*>(Wih + (size_t)g * 1024 + 512 + c * 4);
  ushort4 o; o.x = f2bf(v.x); o.y = f2bf(v.y); o.z = f2bf(v.z); o.w = f2bf(v.w);
  *reinterpret_cast<ushort4*>(Wa + (size_t)g * 512 + c * 4) = o;
}

// ---------------- base[g][b] = input[b]·W_x[g] + b_ih[g] + b_hh[g] ----------------
__global__ __launch_bounds__(256) void base_kernel(const float* __restrict__ x,
    const float* __restrict__ Wih, const float* __restrict__ bih,
    const float* __restrict__ bhh, float* __restrict__ baseT) {
  int t = blockIdx.x * 256 + threadIdx.x;  // 4096*64 threads
  int g = t >> 6, b = t & 63;
  const float4* xv = reinterpret_cast<const float4*>(x + (size_t)b * 512);
  const float4* wv = reinterpret_cast<const float4*>(Wih + (size_t)g * 1024);
  float s = 0.f;
  #pragma unroll 4
  for (int a = 0; a < 128; ++a) {
    float4 xa = xv[a], wa = wv[a];
    s += xa.x * wa.x + xa.y * wa.y + xa.z * wa.z + xa.w * wa.w;
  }
  baseT[t] = s + bih[g] + bhh[g];
}

// ---------------- pre[g][lb] = sum_a Wa[g][a]*acts[lb][a] + base[g][lb%64] ----------------
__global__ __launch_bounds__(256, 1) void gemm_pre(
    const ushort* __restrict__ A,    // Wa bf16 [4096][512]
    const ushort* __restrict__ B,    // acts bf16 [8192][512]
    const float* __restrict__ baseT, // [4096][64]
    ushort* __restrict__ C) {        // pre bf16 [4096][8192]
  __shared__ ushort At[128 * 64];
  __shared__ ushort Bt[128 * 64];
  const int tid = threadIdx.x;
  const int m0 = blockIdx.x * 128;
  const int n0 = blockIdx.y * 128;
  const int wave = tid >> 6, lane = tid & 63;
  const int wm = wave >> 1, wn = wave & 1;
  const int q = lane >> 4, lc = lane & 15;

  f32x4 acc[4][4];
  #pragma unroll
  for (int mt = 0; mt < 4; ++mt)
    #pragma unroll
    for (int nt = 0; nt < 4; ++nt)
      acc[mt][nt] = (f32x4){0.f, 0.f, 0.f, 0.f};

  for (int k0 = 0; k0 < 512; k0 += 64) {
    __syncthreads();
    for (int idx = tid; idx < 1024; idx += 256) {
      int r = idx >> 3, ch = idx & 7;
      *reinterpret_cast<uint4*>(&At[r * 64 + (ch ^ (r & 7)) * 8]) =
          *reinterpret_cast<const uint4*>(A + (size_t)(m0 + r) * 512 + k0 + ch * 8);
      *reinterpret_cast<uint4*>(&Bt[r * 64 + (ch ^ (r & 7)) * 8]) =
          *reinterpret_cast<const uint4*>(B + (size_t)(n0 + r) * 512 + k0 + ch * 8);
    }
    __syncthreads();
    #pragma unroll
    for (int kk = 0; kk < 2; ++kk) {
      bf16x8 af[4], bfr[4];
      #pragma unroll
      for (int mt = 0; mt < 4; ++mt) {
        int r = wm * 64 + mt * 16 + lc;
        af[mt] = *reinterpret_cast<const bf16x8*>(&At[r * 64 + ((kk * 4 + q) ^ (r & 7)) * 8]);
      }
      #pragma unroll
      for (int nt = 0; nt < 4; ++nt) {
        int r = wn * 64 + nt * 16 + lc;
        bfr[nt] = *reinterpret_cast<const bf16x8*>(&Bt[r * 64 + ((kk * 4 + q) ^ (r & 7)) * 8]);
      }
      #pragma unroll
      for (int mt = 0; mt < 4; ++mt)
        #pragma unroll
        for (int nt = 0; nt < 4; ++nt)
          acc[mt][nt] = __builtin_amdgcn_mfma_f32_16x16x32_bf16(af[mt], bfr[nt], acc[mt][nt], 0, 0, 0);
    }
  }
  #pragma unroll
  for (int mt = 0; mt < 4; ++mt) {
    #pragma unroll
    for (int nt = 0; nt < 4; ++nt) {
      int g = m0 + wm * 64 + mt * 16 + q * 4;
      int lb = n0 + wn * 64 + nt * 16 + lc;
      int b = lb & 63;
      #pragma unroll
      for (int i = 0; i < 4; ++i) {
        float v = acc[mt][nt][i] + baseT[(size_t)(g + i) * 64 + b];
        C[(size_t)(g + i) * 8192 + lb] = f2bf(v);
      }
    }
  }
}

// ---------------- persistent LSTM recurrence ----------------
// 64 blocks x 512 threads. Block owns 16 hidden units (64 W_hh rows, 128 KB LDS).
// h exchanged in MFMA-fragment-blocked layout [bg][kk][lane][8] for coalescing.
__global__ __launch_bounds__(512, 1) void lstm_rec(
    const ushort* __restrict__ Whh,  // bf16 [4096][1024]
    const ushort* __restrict__ pre,  // bf16 [4096][8192]
    const float* __restrict__ c0,    // f32 [64][1024]
    ushort* __restrict__ hbuf,       // blocked bf16 [2][4][32][64][8]
    float* __restrict__ out,
    int* __restrict__ flags) {       // [64][32] ints, 128B-padded
  __shared__ ushort wl[64 * 1024];   // 128 KB, XOR-swizzled W_hh slice
  __shared__ ushort hstage[64 * 16]; // h(t+1) staging: [batch][16 units]
  const int tid = threadIdx.x;
  const int bid = blockIdx.x;
  const int j0 = bid * 16;

  // Stage 64 W_hh rows: local row c -> unit j0 + (c>>5)*8 + (c&7), gate (c&31)>>3
  for (int idx = tid; idx < 8192; idx += 512) {
    int c = idx >> 7;
    int ch = idx & 127;  // 16B chunk within row
    int c5 = c & 31;
    int g = j0 + ((c >> 5) << 3) + (c5 & 7) + ((c5 >> 3) << 10);
    uint4 v = *reinterpret_cast<const uint4*>(Whh + (size_t)g * 1024 + ch * 8);
    *reinterpret_cast<uint4*>(&wl[c * 1024 + (ch ^ (c & 7)) * 8]) = v;
  }

  const int wave = tid >> 6;
  const int lane = tid & 63;
  const int q = lane >> 4;
  const int lc = lane & 15;
  const int bg = wave >> 1;             // batch group (0..3)
  const int hh = wave & 1;              // unit half (0..1)
  const int bbase = bg * 16 + q * 4;    // acc row base (batch)
  const bool low = (lc < 8);
  const int j = j0 + hh * 8 + (lc & 7);
  const int ga = j + ((lc >> 3) << 10);  // gate row (i or f) for acc0 col
  const int gb = ga + 2048;              // (g or o) for acc1 col
  const int wrow0 = (hh << 5) + lc;      // wl row for acc0 B-frag
  const int wrow1 = wrow0 + 16;          // for acc1

  float cst[4];
  #pragma unroll
  for (int i = 0; i < 4; ++i)
    cst[i] = low ? c0[(size_t)(bbase + i) * 1024 + j] : 0.f;

  __syncthreads();

  // prefetch pre slice for t=0
  ushort4 pa = *reinterpret_cast<const ushort4*>(pre + (size_t)ga * 8192 + bbase);
  ushort4 pb = *reinterpret_cast<const ushort4*>(pre + (size_t)gb * 8192 + bbase);

  for (int t = 0; t < 128; ++t) {
    const ushort* hp = hbuf + (size_t)(t & 1) * 65536;

    f32x4 acc0, acc1;
    acc0[0] = bf2f(pa.x); acc0[1] = bf2f(pa.y); acc0[2] = bf2f(pa.z); acc0[3] = bf2f(pa.w);
    acc1[0] = bf2f(pb.x); acc1[1] = bf2f(pb.y); acc1[2] = bf2f(pb.z); acc1[3] = bf2f(pb.w);

    // prefetch pre for step t+1 (overlaps MFMA + barrier)
    const int tn = (t < 127) ? t + 1 : t;
    pa = *reinterpret_cast<const ushort4*>(pre + (size_t)ga * 8192 + tn * 64 + bbase);
    pb = *reinterpret_cast<const ushort4*>(pre + (size_t)gb * 8192 + tn * 64 + bbase);

    // gates: acc[16 batches x 16 gate-rows] over K=1024
    // A-frag: coalesced 1KB loads from blocked h; B-frag: LDS W rows
    const ushort* hbg = hp + (size_t)(bg * 32) * 512;
    #pragma unroll
    for (int kk = 0; kk < 32; ++kk) {
      bf16x8 af = *reinterpret_cast<const bf16x8*>(hbg + (size_t)kk * 512 + lane * 8);
      bf16x8 b0 = *reinterpret_cast<const bf16x8*>(&wl[wrow0 * 1024 + ((kk * 4 + q) ^ (lc & 7)) * 8]);
      bf16x8 b1 = *reinterpret_cast<const bf16x8*>(&wl[wrow1 * 1024 + ((kk * 4 + q) ^ (lc & 7)) * 8]);
      acc0 = __builtin_amdgcn_mfma_f32_16x16x32_bf16(af, b0, acc0, 0, 0, 0);
      acc1 = __builtin_amdgcn_mfma_f32_16x16x32_bf16(af, b1, acc1, 0, 0, 0);
    }

    // join i/f and g/o across lane pairs (l <-> l^8), then LSTM cell
    float fv[4], ov[4];
    #pragma unroll
    for (int i = 0; i < 4; ++i) {
      fv[i] = __shfl_xor(acc0[i], 8, 64);
      ov[i] = __shfl_xor(acc1[i], 8, 64);
    }
    float hv[4];
    if (low) {
      #pragma unroll
      for (int i = 0; i < 4; ++i) {
        float ig = 1.f / (1.f + __expf(-acc0[i]));
        float fg = 1.f / (1.f + __expf(-fv[i]));
        float gg = tanhf(acc1[i]);
        float og = 1.f / (1.f + __expf(-ov[i]));
        float cn = fg * cst[i] + ig * gg;
        hv[i] = og * tanhf(cn);
        cst[i] = cn;
        hstage[(size_t)(bbase + i) * 16 + hh * 8 + (lc & 7)] = f2bf(hv[i]);
      }
    }

    if (t == 127) {
      if (low) {
        #pragma unroll
        for (int i = 0; i < 4; ++i) {
          int b = bbase + i;
          out[((size_t)t * 64 + b) * 1024 + j] = hv[i];
          out[HN_OFF + (size_t)b * 1024 + j] = hv[i];
          out[CN_OFF + (size_t)b * 1024 + j] = cst[i];
        }
      }
      break;
    }

    __syncthreads();  // hstage ready

    // export h(t+1): blocked layout, 128 x 16B via 2x8B agent-scope stores
    if (tid < 128) {
      int b = tid >> 1, ci = tid & 1;
      const ull* src = reinterpret_cast<const ull*>(&hstage[b * 16 + ci * 8]);
      size_t de = ((size_t)(b >> 4) * 32 + (bid >> 1)) * 512 +
                  (size_t)((bid & 1) * 2 + ci) * 128 + (size_t)(b & 15) * 8;
      ull* dst = reinterpret_cast<ull*>(hbuf + (size_t)((t + 1) & 1) * 65536 + de);
      __hip_atomic_store(dst, src[0], __ATOMIC_RELAXED, __HIP_MEMORY_SCOPE_AGENT);
      __hip_atomic_store(dst + 1, src[1], __ATOMIC_RELAXED, __HIP_MEMORY_SCOPE_AGENT);
    }
    // drain own stores to the coherence point before publishing
    asm volatile("s_waitcnt vmcnt(0)" ::: "memory");
    __syncthreads();

    // publish immediately, then out-writes overlap the poll window
    if (tid == 0)
      __hip_atomic_store(&flags[bid * 32], t + 1, __ATOMIC_RELAXED,
                         __HIP_MEMORY_SCOPE_AGENT);
    if (low) {
      #pragma unroll
      for (int i = 0; i < 4; ++i)
        out[((size_t)t * 64 + bbase + i) * 1024 + j] = hv[i];
    }

    // poll (wave 0; 64 flags, one per lane, monotonic)
    if (wave == 0) {
      const int target = t + 1;
      for (;;) {
        int a = __hip_atomic_load(&flags[lane * 32], __ATOMIC_RELAXED,
                                  __HIP_MEMORY_SCOPE_AGENT);
        if (__all(a >= target)) break;
        __builtin_amdgcn_s_sleep(1);
      }
      // acquire: invalidate L1/L2 so regular h loads see fresh data
      __builtin_amdgcn_fence(__ATOMIC_ACQUIRE, "agent");
    }
    __syncthreads();
  }
}

extern "C" void kernel_launch(void* const* d_in, const int* in_sizes, int n_in,
                              void* d_out, int out_size, void* d_ws, size_t ws_size,
                              hipStream_t stream) {
  const float* input = (const float*)d_in[0];  // (64,512)
  const float* acts  = (const float*)d_in[1];  // (128,64,512)
  const float* h0    = (const float*)d_in[2];  // (64,1024)
  const float* c0    = (const float*)d_in[3];  // (64,1024)
  const float* Wih   = (const float*)d_in[4];  // (4096,1024)
  const float* Whh   = (const float*)d_in[5];  // (4096,1024)
  const float* bih   = (const float*)d_in[6];  // (4096)
  const float* bhh   = (const float*)d_in[7];  // (4096)
  float* out = (float*)d_out;

  char* ws = (char*)d_ws;
  ushort* pre   = (ushort*)(ws);                 // 67,108,864 B
  ushort* actsb = (ushort*)(ws + 67108864);      //  8,388,608 B
  ushort* Wab   = (ushort*)(ws + 75497472);      //  4,194,304 B
  ushort* Whhb  = (ushort*)(ws + 79691776);      //  8,388,608 B
  float*  baseT = (float*) (ws + 88080384);      //  1,048,576 B
  ushort* hbuf  = (ushort*)(ws + 89128960);      //    262,144 B
  int*    flags = (int*)   (ws + 89391104);      //      8,192 B

  hipMemsetAsync(flags, 0, 8192, stream);
  conv_copy<<<4096, 256, 0, stream>>>(acts, actsb, 1048576);
  conv_copy<<<4096, 256, 0, stream>>>(Whh, Whhb, 1048576);
  conv_h0<<<32, 256, 0, stream>>>(h0, hbuf);
  conv_wa<<<2048, 256, 0, stream>>>(Wih, Wab);
  base_kernel<<<1024, 256, 0, stream>>>(input, Wih, bih, bhh, baseT);
  gemm_pre<<<dim3(32, 64), 256, 0, stream>>>(Wab, actsb, baseT, pre);
  lstm_rec<<<64, 512, 0, stream>>>(Whhb, pre, c0, hbuf, out, flags);
}

// Round 5
// 1051.264 us; speedup vs baseline: 1.9842x; 1.0499x over previous
//
#include <hip/hip_runtime.h>
#include <hip/hip_bf16.h>

typedef __bf16 bf16x8 __attribute__((ext_vector_type(8)));
typedef float f32x4 __attribute__((ext_vector_type(4)));
typedef unsigned long long ull;

// d_out layout (f32): hs[128][64][1024] | h_n[64][1024] | c_n[64][1024]
#define HN_OFF 8388608u
#define CN_OFF 8454144u

__device__ __forceinline__ float bf2f(ushort u) {
  union { unsigned int i; float f; } x; x.i = ((unsigned int)u) << 16; return x.f;
}
__device__ __forceinline__ ushort f2bf(float f) {
  union { float f; unsigned int i; } x; x.f = f;
  unsigned int r = x.i + 0x7FFFu + ((x.i >> 16) & 1u);
  return (ushort)(r >> 16);
}

// ---------------- f32 -> bf16 converters ----------------
__global__ __launch_bounds__(256) void conv_copy(const float* __restrict__ s,
                                                 ushort* __restrict__ d, int n4) {
  int i = blockIdx.x * 256 + threadIdx.x;
  if (i < n4) {
    float4 v = reinterpret_cast<const float4*>(s)[i];
    ushort4 o; o.x = f2bf(v.x); o.y = f2bf(v.y); o.z = f2bf(v.z); o.w = f2bf(v.w);
    reinterpret_cast<ushort4*>(d)[i] = o;
  }
}

// h0 (64x1024 f32) -> blocked bf16 layout [bg(4)][kk(32)][lane(64)][8]
__global__ __launch_bounds__(256) void conv_h0(const float* __restrict__ h0,
                                               ushort* __restrict__ hb) {
  int t = blockIdx.x * 256 + threadIdx.x;  // 8192 threads: b = t>>7, chunk c = t&127
  int b = t >> 7, c = t & 127;             // j = c*8
  float4 v0 = *reinterpret_cast<const float4*>(h0 + (size_t)b * 1024 + c * 8);
  float4 v1 = *reinterpret_cast<const float4*>(h0 + (size_t)b * 1024 + c * 8 + 4);
  size_t de = ((size_t)(b >> 4) * 32 + (c >> 2)) * 512 + (size_t)(c & 3) * 128 + (b & 15) * 8;
  ushort* d = hb + de;
  d[0] = f2bf(v0.x); d[1] = f2bf(v0.y); d[2] = f2bf(v0.z); d[3] = f2bf(v0.w);
  d[4] = f2bf(v1.x); d[5] = f2bf(v1.y); d[6] = f2bf(v1.z); d[7] = f2bf(v1.w);
}

// Extract W_a = W_ih[:, 512:1024] -> bf16 [4096][512]
__global__ __launch_bounds__(256) void conv_wa(const float* __restrict__ Wih,
                                               ushort* __restrict__ Wa) {
  int t = blockIdx.x * 256 + threadIdx.x;  // 4096*128 threads
  int g = t >> 7, c = t & 127;
  float4 v = *reinterpret_cast<const float4*>(Wih + (size_t)g * 1024 + 512 + c * 4);
  ushort4 o; o.x = f2bf(v.x); o.y = f2bf(v.y); o.z = f2bf(v.z); o.w = f2bf(v.w);
  *reinterpret_cast<ushort4*>(Wa + (size_t)g * 512 + c * 4) = o;
}

// ---------------- base[g][b] = input[b]·W_x[g] + b_ih[g] + b_hh[g] ----------------
__global__ __launch_bounds__(256) void base_kernel(const float* __restrict__ x,
    const float* __restrict__ Wih, const float* __restrict__ bih,
    const float* __restrict__ bhh, float* __restrict__ baseT) {
  int t = blockIdx.x * 256 + threadIdx.x;  // 4096*64 threads
  int g = t >> 6, b = t & 63;
  const float4* xv = reinterpret_cast<const float4*>(x + (size_t)b * 512);
  const float4* wv = reinterpret_cast<const float4*>(Wih + (size_t)g * 1024);
  float s = 0.f;
  #pragma unroll 4
  for (int a = 0; a < 128; ++a) {
    float4 xa = xv[a], wa = wv[a];
    s += xa.x * wa.x + xa.y * wa.y + xa.z * wa.z + xa.w * wa.w;
  }
  baseT[t] = s + bih[g] + bhh[g];
}

// ---------------- pre[g][lb] = sum_a Wa[g][a]*acts[lb][a] + base[g][lb%64] ----------------
__global__ __launch_bounds__(256, 1) void gemm_pre(
    const ushort* __restrict__ A,    // Wa bf16 [4096][512]
    const ushort* __restrict__ B,    // acts bf16 [8192][512]
    const float* __restrict__ baseT, // [4096][64]
    ushort* __restrict__ C) {        // pre bf16 [4096][8192]
  __shared__ ushort At[128 * 64];
  __shared__ ushort Bt[128 * 64];
  const int tid = threadIdx.x;
  const int m0 = blockIdx.x * 128;
  const int n0 = blockIdx.y * 128;
  const int wave = tid >> 6, lane = tid & 63;
  const int wm = wave >> 1, wn = wave & 1;
  const int q = lane >> 4, lc = lane & 15;

  f32x4 acc[4][4];
  #pragma unroll
  for (int mt = 0; mt < 4; ++mt)
    #pragma unroll
    for (int nt = 0; nt < 4; ++nt)
      acc[mt][nt] = (f32x4){0.f, 0.f, 0.f, 0.f};

  for (int k0 = 0; k0 < 512; k0 += 64) {
    __syncthreads();
    for (int idx = tid; idx < 1024; idx += 256) {
      int r = idx >> 3, ch = idx & 7;
      *reinterpret_cast<uint4*>(&At[r * 64 + (ch ^ (r & 7)) * 8]) =
          *reinterpret_cast<const uint4*>(A + (size_t)(m0 + r) * 512 + k0 + ch * 8);
      *reinterpret_cast<uint4*>(&Bt[r * 64 + (ch ^ (r & 7)) * 8]) =
          *reinterpret_cast<const uint4*>(B + (size_t)(n0 + r) * 512 + k0 + ch * 8);
    }
    __syncthreads();
    #pragma unroll
    for (int kk = 0; kk < 2; ++kk) {
      bf16x8 af[4], bfr[4];
      #pragma unroll
      for (int mt = 0; mt < 4; ++mt) {
        int r = wm * 64 + mt * 16 + lc;
        af[mt] = *reinterpret_cast<const bf16x8*>(&At[r * 64 + ((kk * 4 + q) ^ (r & 7)) * 8]);
      }
      #pragma unroll
      for (int nt = 0; nt < 4; ++nt) {
        int r = wn * 64 + nt * 16 + lc;
        bfr[nt] = *reinterpret_cast<const bf16x8*>(&Bt[r * 64 + ((kk * 4 + q) ^ (r & 7)) * 8]);
      }
      #pragma unroll
      for (int mt = 0; mt < 4; ++mt)
        #pragma unroll
        for (int nt = 0; nt < 4; ++nt)
          acc[mt][nt] = __builtin_amdgcn_mfma_f32_16x16x32_bf16(af[mt], bfr[nt], acc[mt][nt], 0, 0, 0);
    }
  }
  #pragma unroll
  for (int mt = 0; mt < 4; ++mt) {
    #pragma unroll
    for (int nt = 0; nt < 4; ++nt) {
      int g = m0 + wm * 64 + mt * 16 + q * 4;
      int lb = n0 + wn * 64 + nt * 16 + lc;
      int b = lb & 63;
      #pragma unroll
      for (int i = 0; i < 4; ++i) {
        float v = acc[mt][nt][i] + baseT[(size_t)(g + i) * 64 + b];
        C[(size_t)(g + i) * 8192 + lb] = f2bf(v);
      }
    }
  }
}

// ---------------- persistent LSTM recurrence (dataflow sync, no fences) -----
// 64 blocks x 512 threads. Block owns 16 hidden units (64 W_hh rows in LDS,
// conflict-free [chunk][row^(c&7)] layout). h exchanged via MALL: producers
// store with agent scope, consumers load with sc0 sc1 (bypass L1/L2), so no
// cache invalidation is ever needed. Sync = 64 monotonic flags, wave-0
// gather + ballot. h chunk loads: 32 in flight, counted vmcnt group waits.
#define WAITG(n) asm volatile("s_waitcnt vmcnt(" #n ")" ::: "memory"); \
                 __builtin_amdgcn_sched_barrier(0);

__global__ __launch_bounds__(512, 1) void lstm_rec(
    const ushort* __restrict__ Whh,  // bf16 [4096][1024]
    const ushort* __restrict__ pre,  // bf16 [4096][8192]
    const float* __restrict__ c0,    // f32 [64][1024]
    const ushort* __restrict__ hbuf, // blocked bf16 [2][4][32][64][8] (read base)
    ushort* __restrict__ hbw,        // same buffer, write alias
    float* __restrict__ out,
    int* __restrict__ flags) {       // [64] ints at 16B stride
  __shared__ ushort wl[64 * 1024];   // 128 KB W slice, conflict-free layout
  __shared__ ushort hstage[64 * 16];
  const int tid = threadIdx.x;
  const int bid = blockIdx.x;
  const int j0 = bid * 16;

  // Stage W: LDS slot (c, r) holds gate-row G(r^(c&7)) chunk c, where
  // G(r) = j0 + (r>>5)*8 + (r&7) + (((r>>4)&1)*2 + ((r>>3)&1))*1024
  for (int idx = tid; idx < 8192; idx += 512) {
    int ch = idx & 127;  // 16B chunk within K (= kk*4+q)
    int r = idx >> 7;    // 0..63
    int lcr = r & 15, sel = (r >> 4) & 1, hh2 = r >> 5;
    int g = j0 + hh2 * 8 + (lcr & 7) + ((sel * 2 + (lcr >> 3)) << 10);
    uint4 v = *reinterpret_cast<const uint4*>(Whh + (size_t)g * 1024 + ch * 8);
    *reinterpret_cast<uint4*>(&wl[(ch * 64 + (r ^ (ch & 7))) * 8]) = v;
  }

  const int wave = tid >> 6;
  const int lane = tid & 63;
  const int q = lane >> 4;
  const int lc = lane & 15;
  const int bg = wave >> 1;             // batch group (0..3)
  const int hh = wave & 1;              // unit half (0..1)
  const int bbase = bg * 16 + q * 4;    // acc row base (batch)
  const bool low = (lc < 8);
  const int j = j0 + hh * 8 + (lc & 7);
  const int ga = j + ((lc >> 3) << 10);  // gate row (i or f) for acc0 col
  const unsigned va_base = ((unsigned)ga * 8192u + (unsigned)bbase) * 2u;
  const int wrow0 = (hh << 5) + lc;      // W row index for acc0 B-frag
  // voffset base for h loads (bytes): bg<<15 | lane<<4; +(t&1)<<17; +kk<<10
  const unsigned hoff_base = ((unsigned)bg << 15) | ((unsigned)lane << 4);

  float cst[4];
  #pragma unroll
  for (int i = 0; i < 4; ++i)
    cst[i] = low ? c0[(size_t)(bbase + i) * 1024 + j] : 0.f;

  __syncthreads();

  // pre slice for t=0 (compiler-managed loads)
  ushort4 pa = *reinterpret_cast<const ushort4*>(pre + (size_t)ga * 8192 + bbase);
  ushort4 pb = *reinterpret_cast<const ushort4*>(pre + ((size_t)ga + 2048) * 8192 + bbase);

  for (int t = 0; t < 128; ++t) {
    // gate: wave 0 spins until every producer published h(t)
    if (t > 0 && wave == 0) {
      for (;;) {
        int f = __hip_atomic_load(&flags[lane * 4], __ATOMIC_RELAXED,
                                  __HIP_MEMORY_SCOPE_AGENT);
        if (__all(f >= t)) break;
      }
    }
    __syncthreads();  // compiler drains vmcnt before s_barrier: count resets to 0

    f32x4 acc0, acc1;
    acc0[0] = bf2f(pa.x); acc0[1] = bf2f(pa.y); acc0[2] = bf2f(pa.z); acc0[3] = bf2f(pa.w);
    acc1[0] = bf2f(pb.x); acc1[1] = bf2f(pb.y); acc1[2] = bf2f(pb.z); acc1[3] = bf2f(pb.w);

    // issue pre prefetch for t+1 (asm; first 2 in this iteration's VMEM queue)
    const int tn = (t < 127) ? t + 1 : t;
    unsigned va = va_base + (unsigned)tn * 128u;
    unsigned vb = va + 33554432u;  // +2048 rows * 8192 * 2B
    ushort4 npa, npb;
    asm volatile("global_load_dwordx2 %0, %1, %2" : "=v"(npa) : "v"(va), "s"(pre));
    asm volatile("global_load_dwordx2 %0, %1, %2" : "=v"(npb) : "v"(vb), "s"(pre));

    // issue all 32 h-chunk loads (sc0 sc1: bypass L1/L2, read at MALL)
    const unsigned hob = hoff_base | ((unsigned)(t & 1) << 17);
    bf16x8 haf[32];
    #pragma unroll
    for (int kk = 0; kk < 32; ++kk) {
      unsigned voff = hob + ((unsigned)kk << 10);
      asm volatile("global_load_dwordx4 %0, %1, %2 sc0 sc1"
                   : "=v"(haf[kk]) : "v"(voff), "s"(hbuf));
    }

    // MFMA stream in 4 groups; haf[k] ready when vmcnt <= 31-k (+2 pre loads)
    #define GRP(base)                                                          \
      _Pragma("unroll")                                                        \
      for (int kk = base; kk < base + 8; ++kk) {                               \
        int c = kk * 4 + q;                                                    \
        bf16x8 b0 = *reinterpret_cast<const bf16x8*>(                          \
            &wl[(c * 64 + (wrow0 ^ (c & 7))) * 8]);                            \
        bf16x8 b1 = *reinterpret_cast<const bf16x8*>(                          \
            &wl[(c * 64 + ((wrow0 + 16) ^ (c & 7))) * 8]);                     \
        acc0 = __builtin_amdgcn_mfma_f32_16x16x32_bf16(haf[kk], b0, acc0, 0, 0, 0); \
        acc1 = __builtin_amdgcn_mfma_f32_16x16x32_bf16(haf[kk], b1, acc1, 0, 0, 0); \
      }
    WAITG(24) GRP(0)
    WAITG(16) GRP(8)
    WAITG(8)  GRP(16)
    WAITG(0)  GRP(24)
    #undef GRP

    // join i/f and g/o across lane pairs (l <-> l^8), then LSTM cell
    float fv[4], ov[4];
    #pragma unroll
    for (int i = 0; i < 4; ++i) {
      fv[i] = __shfl_xor(acc0[i], 8, 64);
      ov[i] = __shfl_xor(acc1[i], 8, 64);
    }
    float hv[4];
    if (low) {
      #pragma unroll
      for (int i = 0; i < 4; ++i) {
        float ig = 1.f / (1.f + __expf(-acc0[i]));
        float fg = 1.f / (1.f + __expf(-fv[i]));
        float gg = tanhf(acc1[i]);
        float og = 1.f / (1.f + __expf(-ov[i]));
        float cn = fg * cst[i] + ig * gg;
        hv[i] = og * tanhf(cn);
        cst[i] = cn;
        hstage[(size_t)(bbase + i) * 16 + hh * 8 + (lc & 7)] = f2bf(hv[i]);
      }
    }

    if (t == 127) {
      if (low) {
        #pragma unroll
        for (int i = 0; i < 4; ++i) {
          int b = bbase + i;
          out[((size_t)t * 64 + b) * 1024 + j] = hv[i];
          out[HN_OFF + (size_t)b * 1024 + j] = hv[i];
          out[CN_OFF + (size_t)b * 1024 + j] = cst[i];
        }
      }
      break;
    }

    __syncthreads();  // hstage ready

    // export h(t+1): blocked layout, agent-scope stores (reach MALL)
    if (tid < 128) {
      int b = tid >> 1, ci = tid & 1;
      const ull* src = reinterpret_cast<const ull*>(&hstage[b * 16 + ci * 8]);
      size_t de = ((size_t)(b >> 4) * 32 + (bid >> 1)) * 512 +
                  (size_t)((bid & 1) * 2 + ci) * 128 + (size_t)(b & 15) * 8;
      ull* dst = reinterpret_cast<ull*>(hbw + (size_t)((t + 1) & 1) * 65536 + de);
      __hip_atomic_store(dst, src[0], __ATOMIC_RELAXED, __HIP_MEMORY_SCOPE_AGENT);
      __hip_atomic_store(dst + 1, src[1], __ATOMIC_RELAXED, __HIP_MEMORY_SCOPE_AGENT);
    }
    // drain this wave's export stores, then block-wide join before publish
    asm volatile("s_waitcnt vmcnt(0)" ::: "memory");
    __syncthreads();

    if (tid == 0)
      __hip_atomic_store(&flags[bid * 4], t + 1, __ATOMIC_RELAXED,
                         __HIP_MEMORY_SCOPE_AGENT);

    // out-writes overlap other blocks' consumption
    if (low) {
      #pragma unroll
      for (int i = 0; i < 4; ++i)
        out[((size_t)t * 64 + bbase + i) * 1024 + j] = hv[i];
    }

    pa = npa; pb = npb;
  }
}

extern "C" void kernel_launch(void* const* d_in, const int* in_sizes, int n_in,
                              void* d_out, int out_size, void* d_ws, size_t ws_size,
                              hipStream_t stream) {
  const float* input = (const float*)d_in[0];  // (64,512)
  const float* acts  = (const float*)d_in[1];  // (128,64,512)
  const float* h0    = (const float*)d_in[2];  // (64,1024)
  const float* c0    = (const float*)d_in[3];  // (64,1024)
  const float* Wih   = (const float*)d_in[4];  // (4096,1024)
  const float* Whh   = (const float*)d_in[5];  // (4096,1024)
  const float* bih   = (const float*)d_in[6];  // (4096)
  const float* bhh   = (const float*)d_in[7];  // (4096)
  float* out = (float*)d_out;

  char* ws = (char*)d_ws;
  ushort* pre   = (ushort*)(ws);                 // 67,108,864 B
  ushort* actsb = (ushort*)(ws + 67108864);      //  8,388,608 B
  ushort* Wab   = (ushort*)(ws + 75497472);      //  4,194,304 B
  ushort* Whhb  = (ushort*)(ws + 79691776);      //  8,388,608 B
  float*  baseT = (float*) (ws + 88080384);      //  1,048,576 B
  ushort* hbuf  = (ushort*)(ws + 89128960);      //    262,144 B
  int*    flags = (int*)   (ws + 89391104);      //      8,192 B

  hipMemsetAsync(flags, 0, 8192, stream);
  conv_copy<<<4096, 256, 0, stream>>>(acts, actsb, 1048576);
  conv_copy<<<4096, 256, 0, stream>>>(Whh, Whhb, 1048576);
  conv_h0<<<32, 256, 0, stream>>>(h0, hbuf);
  conv_wa<<<2048, 256, 0, stream>>>(Wih, Wab);
  base_kernel<<<1024, 256, 0, stream>>>(input, Wih, bih, bhh, baseT);
  gemm_pre<<<dim3(32, 64), 256, 0, stream>>>(Wab, actsb, baseT, pre);
  lstm_rec<<<64, 512, 0, stream>>>(Whhb, pre, c0, hbuf, hbuf, out, flags);
}

// Round 6
// 735.934 us; speedup vs baseline: 2.8343x; 1.4285x over previous
//
#include <hip/hip_runtime.h>
#include <hip/hip_bf16.h>

typedef __bf16 bf16x8 __attribute__((ext_vector_type(8)));
typedef float f32x4 __attribute__((ext_vector_type(4)));
typedef unsigned long long ull;

// d_out layout (f32): hs[128][64][1024] | h_n[64][1024] | c_n[64][1024]
#define HN_OFF 8388608u
#define CN_OFF 8454144u

__device__ __forceinline__ float bf2f(ushort u) {
  union { unsigned int i; float f; } x; x.i = ((unsigned int)u) << 16; return x.f;
}
__device__ __forceinline__ ushort f2bf(float f) {
  union { float f; unsigned int i; } x; x.f = f;
  unsigned int r = x.i + 0x7FFFu + ((x.i >> 16) & 1u);
  return (ushort)(r >> 16);
}

// ---------------- f32 -> bf16 converters ----------------
__global__ __launch_bounds__(256) void conv_copy(const float* __restrict__ s,
                                                 ushort* __restrict__ d, int n4) {
  int i = blockIdx.x * 256 + threadIdx.x;
  if (i < n4) {
    float4 v = reinterpret_cast<const float4*>(s)[i];
    ushort4 o; o.x = f2bf(v.x); o.y = f2bf(v.y); o.z = f2bf(v.z); o.w = f2bf(v.w);
    reinterpret_cast<ushort4*>(d)[i] = o;
  }
}

// h0 (64x1024 f32) -> blocked bf16 layout [bg(4)][kk(32)][lane(64)][8]
__global__ __launch_bounds__(256) void conv_h0(const float* __restrict__ h0,
                                               ushort* __restrict__ hb) {
  int t = blockIdx.x * 256 + threadIdx.x;  // 8192 threads: b = t>>7, chunk c = t&127
  int b = t >> 7, c = t & 127;             // j = c*8
  float4 v0 = *reinterpret_cast<const float4*>(h0 + (size_t)b * 1024 + c * 8);
  float4 v1 = *reinterpret_cast<const float4*>(h0 + (size_t)b * 1024 + c * 8 + 4);
  size_t de = ((size_t)(b >> 4) * 32 + (c >> 2)) * 512 + (size_t)(c & 3) * 128 + (b & 15) * 8;
  ushort* d = hb + de;
  d[0] = f2bf(v0.x); d[1] = f2bf(v0.y); d[2] = f2bf(v0.z); d[3] = f2bf(v0.w);
  d[4] = f2bf(v1.x); d[5] = f2bf(v1.y); d[6] = f2bf(v1.z); d[7] = f2bf(v1.w);
}

// Extract W_a = W_ih[:, 512:1024] -> bf16 [4096][512]
__global__ __launch_bounds__(256) void conv_wa(const float* __restrict__ Wih,
                                               ushort* __restrict__ Wa) {
  int t = blockIdx.x * 256 + threadIdx.x;  // 4096*128 threads
  int g = t >> 7, c = t & 127;
  float4 v = *reinterpret_cast<const float4*>(Wih + (size_t)g * 1024 + 512 + c * 4);
  ushort4 o; o.x = f2bf(v.x); o.y = f2bf(v.y); o.z = f2bf(v.z); o.w = f2bf(v.w);
  *reinterpret_cast<ushort4*>(Wa + (size_t)g * 512 + c * 4) = o;
}

// ---------------- base[g][b] = input[b]·W_x[g] + b_ih[g] + b_hh[g] ----------------
__global__ __launch_bounds__(256) void base_kernel(const float* __restrict__ x,
    const float* __restrict__ Wih, const float* __restrict__ bih,
    const float* __restrict__ bhh, float* __restrict__ baseT) {
  int t = blockIdx.x * 256 + threadIdx.x;  // 4096*64 threads
  int g = t >> 6, b = t & 63;
  const float4* xv = reinterpret_cast<const float4*>(x + (size_t)b * 512);
  const float4* wv = reinterpret_cast<const float4*>(Wih + (size_t)g * 1024);
  float s = 0.f;
  #pragma unroll 4
  for (int a = 0; a < 128; ++a) {
    float4 xa = xv[a], wa = wv[a];
    s += xa.x * wa.x + xa.y * wa.y + xa.z * wa.z + xa.w * wa.w;
  }
  baseT[t] = s + bih[g] + bhh[g];
}

// ---------------- pre[g][lb] = sum_a Wa[g][a]*acts[lb][a] + base[g][lb%64] ----------------
__global__ __launch_bounds__(256, 1) void gemm_pre(
    const ushort* __restrict__ A,    // Wa bf16 [4096][512]
    const ushort* __restrict__ B,    // acts bf16 [8192][512]
    const float* __restrict__ baseT, // [4096][64]
    ushort* __restrict__ C) {        // pre bf16 [4096][8192]
  __shared__ ushort At[128 * 64];
  __shared__ ushort Bt[128 * 64];
  const int tid = threadIdx.x;
  const int m0 = blockIdx.x * 128;
  const int n0 = blockIdx.y * 128;
  const int wave = tid >> 6, lane = tid & 63;
  const int wm = wave >> 1, wn = wave & 1;
  const int q = lane >> 4, lc = lane & 15;

  f32x4 acc[4][4];
  #pragma unroll
  for (int mt = 0; mt < 4; ++mt)
    #pragma unroll
    for (int nt = 0; nt < 4; ++nt)
      acc[mt][nt] = (f32x4){0.f, 0.f, 0.f, 0.f};

  for (int k0 = 0; k0 < 512; k0 += 64) {
    __syncthreads();
    for (int idx = tid; idx < 1024; idx += 256) {
      int r = idx >> 3, ch = idx & 7;
      *reinterpret_cast<uint4*>(&At[r * 64 + (ch ^ (r & 7)) * 8]) =
          *reinterpret_cast<const uint4*>(A + (size_t)(m0 + r) * 512 + k0 + ch * 8);
      *reinterpret_cast<uint4*>(&Bt[r * 64 + (ch ^ (r & 7)) * 8]) =
          *reinterpret_cast<const uint4*>(B + (size_t)(n0 + r) * 512 + k0 + ch * 8);
    }
    __syncthreads();
    #pragma unroll
    for (int kk = 0; kk < 2; ++kk) {
      bf16x8 af[4], bfr[4];
      #pragma unroll
      for (int mt = 0; mt < 4; ++mt) {
        int r = wm * 64 + mt * 16 + lc;
        af[mt] = *reinterpret_cast<const bf16x8*>(&At[r * 64 + ((kk * 4 + q) ^ (r & 7)) * 8]);
      }
      #pragma unroll
      for (int nt = 0; nt < 4; ++nt) {
        int r = wn * 64 + nt * 16 + lc;
        bfr[nt] = *reinterpret_cast<const bf16x8*>(&Bt[r * 64 + ((kk * 4 + q) ^ (r & 7)) * 8]);
      }
      #pragma unroll
      for (int mt = 0; mt < 4; ++mt)
        #pragma unroll
        for (int nt = 0; nt < 4; ++nt)
          acc[mt][nt] = __builtin_amdgcn_mfma_f32_16x16x32_bf16(af[mt], bfr[nt], acc[mt][nt], 0, 0, 0);
    }
  }
  #pragma unroll
  for (int mt = 0; mt < 4; ++mt) {
    #pragma unroll
    for (int nt = 0; nt < 4; ++nt) {
      int g = m0 + wm * 64 + mt * 16 + q * 4;
      int lb = n0 + wn * 64 + nt * 16 + lc;
      int b = lb & 63;
      #pragma unroll
      for (int i = 0; i < 4; ++i) {
        float v = acc[mt][nt][i] + baseT[(size_t)(g + i) * 64 + b];
        C[(size_t)(g + i) * 8192 + lb] = f2bf(v);
      }
    }
  }
}

// ---------------- persistent LSTM recurrence: W in registers, 4 planes ------
// 256 blocks x 256 threads (4 waves). Block (ug = bid>>2, bq = bid&3) computes
// units ug*16..+16 for batch quarter bq. Wave w owns 16 gate rows =
// units ug*16+w*4..+4 x 4 gates, W fragments resident in 128 VGPRs (loaded
// once, zero per-step W traffic). h exchange: R5's proven protocol —
// producers agent-scope stores to MALL, consumers sc0 sc1 bypass loads,
// per-plane 64 monotonic flags, wave-0 spin. i/f/g/o joined via shfl_xor.
#define WAITG(n) asm volatile("s_waitcnt vmcnt(" #n ")" ::: "memory"); \
                 __builtin_amdgcn_sched_barrier(0);

__global__ __launch_bounds__(256, 1) void lstm_rec(
    const ushort* __restrict__ Whh,  // bf16 [4096][1024]
    const ushort* __restrict__ pre,  // bf16 [4096][8192]
    const float* __restrict__ c0,    // f32 [64][1024]
    const ushort* __restrict__ hbuf, // blocked bf16 [2][4][32][64][8] (read)
    ushort* __restrict__ hbw,        // same buffer, write alias
    float* __restrict__ out,
    int* __restrict__ flags) {       // [4 planes][64] ints at 16B stride
  __shared__ ushort hstage[16 * 16]; // [batch-local 16][unit-local 16]
  const int tid = threadIdx.x;
  const int bid = blockIdx.x;
  const int bq = bid & 3;            // batch-quarter plane
  const int ug = bid >> 2;           // unit group (0..63)
  const int w = tid >> 6;            // wave = row subgroup
  const int lane = tid & 63;
  const int q = lane >> 4;
  const int lc = lane & 15;
  const int ul = w * 4 + (lc & 3);             // unit-local (0..15)
  const int u = ug * 16 + ul;                  // hidden unit for this column
  const int gr = u + ((lc >> 2) << 10);        // gate row (gate = lc>>2)
  const int bbase = bq * 16 + q * 4;           // global batch base for acc rows
  const bool cellLane = ((lc & 12) == 0);      // lc in 0..3 -> owns unit u

  // ---- W_hh fragments resident in registers (one acc tile: 16b x 16g) ----
  bf16x8 wfr[32];
  {
    const ushort* wr = Whh + (size_t)gr * 1024 + q * 8;
    #pragma unroll
    for (int kk = 0; kk < 32; ++kk)
      wfr[kk] = *reinterpret_cast<const bf16x8*>(wr + kk * 32);
  }

  float cst[4];
  #pragma unroll
  for (int i = 0; i < 4; ++i)
    cst[i] = cellLane ? c0[(size_t)(bbase + i) * 1024 + u] : 0.f;

  const unsigned va_base = ((unsigned)gr * 8192u + (unsigned)bbase) * 2u;
  const unsigned hob0 = ((unsigned)bq << 15) | ((unsigned)lane << 4);

  // pre slice for t=0
  ushort4 pa = *reinterpret_cast<const ushort4*>(pre + (size_t)gr * 8192 + bbase);

  for (int t = 0; t < 128; ++t) {
    // gate: wave 0 spins until all 64 producers of this plane published h(t)
    if (t > 0 && w == 0) {
      for (;;) {
        int f = __hip_atomic_load(&flags[(bq * 64 + lane) * 4], __ATOMIC_RELAXED,
                                  __HIP_MEMORY_SCOPE_AGENT);
        if (__all(f >= t)) break;
      }
    }
    __syncthreads();

    f32x4 acc;
    acc[0] = bf2f(pa.x); acc[1] = bf2f(pa.y); acc[2] = bf2f(pa.z); acc[3] = bf2f(pa.w);

    // pre prefetch for t+1 (first in this iteration's VMEM queue)
    const int tn = (t < 127) ? t + 1 : t;
    unsigned va = va_base + (unsigned)tn * 128u;
    ushort4 npa;
    asm volatile("global_load_dwordx2 %0, %1, %2" : "=v"(npa) : "v"(va), "s"(pre));

    // issue all 32 h-chunk loads (sc0 sc1: bypass L1/L2, read at MALL)
    const unsigned hob = hob0 | ((unsigned)(t & 1) << 17);
    bf16x8 haf[32];
    #pragma unroll
    for (int kk = 0; kk < 32; ++kk) {
      unsigned voff = hob + ((unsigned)kk << 10);
      asm volatile("global_load_dwordx4 %0, %1, %2 sc0 sc1"
                   : "=v"(haf[kk]) : "v"(voff), "s"(hbuf));
    }

    // MFMA stream: 4 groups of 8; haf[k] ready when vmcnt <= (32+1)-1-k
    #define GRP(base)                                                          \
      _Pragma("unroll")                                                        \
      for (int kk = base; kk < base + 8; ++kk)                                 \
        acc = __builtin_amdgcn_mfma_f32_16x16x32_bf16(haf[kk], wfr[kk], acc, 0, 0, 0);
    WAITG(24) GRP(0)
    WAITG(16) GRP(8)
    WAITG(8)  GRP(16)
    WAITG(0)  GRP(24)
    #undef GRP

    // join i/f/g/o across lanes (unit u at lanes lc, lc^4, lc^8, lc^12)
    float fv[4], gv[4], ov[4];
    #pragma unroll
    for (int i = 0; i < 4; ++i) {
      fv[i] = __shfl_xor(acc[i], 4, 64);
      gv[i] = __shfl_xor(acc[i], 8, 64);
      ov[i] = __shfl_xor(acc[i], 12, 64);
    }
    float hv[4];
    if (cellLane) {
      #pragma unroll
      for (int i = 0; i < 4; ++i) {
        float ig = 1.f / (1.f + __expf(-acc[i]));
        float fg = 1.f / (1.f + __expf(-fv[i]));
        float gg = tanhf(gv[i]);
        float og = 1.f / (1.f + __expf(-ov[i]));
        float cn = fg * cst[i] + ig * gg;
        hv[i] = og * tanhf(cn);
        cst[i] = cn;
        hstage[(q * 4 + i) * 16 + ul] = f2bf(hv[i]);
      }
    }

    if (t == 127) {
      if (cellLane) {
        #pragma unroll
        for (int i = 0; i < 4; ++i) {
          int b = bbase + i;
          out[((size_t)t * 64 + b) * 1024 + u] = hv[i];
          out[HN_OFF + (size_t)b * 1024 + u] = hv[i];
          out[CN_OFF + (size_t)b * 1024 + u] = cst[i];
        }
      }
      break;
    }

    __syncthreads();  // hstage ready

    // export h(t+1): wave 0 only (32 threads x 16B), then drain + publish.
    // Export, drain, and flag all within wave 0 -> wave-local ordering works.
    if (tid < 32) {
      int bl = tid >> 1, ci = tid & 1;
      const ull* src = reinterpret_cast<const ull*>(&hstage[bl * 16 + ci * 8]);
      size_t de = ((size_t)((t + 1) & 1) << 16) + ((size_t)bq << 14) +
                  ((size_t)(ug >> 1) << 9) +
                  (size_t)(((ug * 2 + ci) & 3) * 16 + bl) * 8;
      ull* dst = reinterpret_cast<ull*>(hbw + de);
      __hip_atomic_store(dst, src[0], __ATOMIC_RELAXED, __HIP_MEMORY_SCOPE_AGENT);
      __hip_atomic_store(dst + 1, src[1], __ATOMIC_RELAXED, __HIP_MEMORY_SCOPE_AGENT);
    }
    if (w == 0) {
      asm volatile("s_waitcnt vmcnt(0)" ::: "memory");
      if (tid == 0)
        __hip_atomic_store(&flags[(bq * 64 + ug) * 4], t + 1, __ATOMIC_RELAXED,
                           __HIP_MEMORY_SCOPE_AGENT);
    }

    // hs out-writes overlap other blocks' consumption
    if (cellLane) {
      #pragma unroll
      for (int i = 0; i < 4; ++i)
        out[((size_t)t * 64 + bbase + i) * 1024 + u] = hv[i];
    }

    pa = npa;
  }
}

extern "C" void kernel_launch(void* const* d_in, const int* in_sizes, int n_in,
                              void* d_out, int out_size, void* d_ws, size_t ws_size,
                              hipStream_t stream) {
  const float* input = (const float*)d_in[0];  // (64,512)
  const float* acts  = (const float*)d_in[1];  // (128,64,512)
  const float* h0    = (const float*)d_in[2];  // (64,1024)
  const float* c0    = (const float*)d_in[3];  // (64,1024)
  const float* Wih   = (const float*)d_in[4];  // (4096,1024)
  const float* Whh   = (const float*)d_in[5];  // (4096,1024)
  const float* bih   = (const float*)d_in[6];  // (4096)
  const float* bhh   = (const float*)d_in[7];  // (4096)
  float* out = (float*)d_out;

  char* ws = (char*)d_ws;
  ushort* pre   = (ushort*)(ws);                 // 67,108,864 B
  ushort* actsb = (ushort*)(ws + 67108864);      //  8,388,608 B
  ushort* Wab   = (ushort*)(ws + 75497472);      //  4,194,304 B
  ushort* Whhb  = (ushort*)(ws + 79691776);      //  8,388,608 B
  float*  baseT = (float*) (ws + 88080384);      //  1,048,576 B
  ushort* hbuf  = (ushort*)(ws + 89128960);      //    262,144 B
  int*    flags = (int*)   (ws + 89391104);      //      8,192 B

  hipMemsetAsync(flags, 0, 8192, stream);
  conv_copy<<<4096, 256, 0, stream>>>(acts, actsb, 1048576);
  conv_copy<<<4096, 256, 0, stream>>>(Whh, Whhb, 1048576);
  conv_h0<<<32, 256, 0, stream>>>(h0, hbuf);
  conv_wa<<<2048, 256, 0, stream>>>(Wih, Wab);
  base_kernel<<<1024, 256, 0, stream>>>(input, Wih, bih, bhh, baseT);
  gemm_pre<<<dim3(32, 64), 256, 0, stream>>>(Wab, actsb, baseT, pre);
  lstm_rec<<<256, 256, 0, stream>>>(Whhb, pre, c0, hbuf, hbuf, out, flags);
}